// Round 2
// baseline (272.144 us; speedup 1.0000x reference)
//
#include <hip/hip_runtime.h>
#include <stdint.h>

#define NINPUTS   1024
#define NOUTPUTS  1024
#define NMID      31          // NUM_LAYERS - 1 middle layers
#define NN        4096        // neurons per layer
#define W         65536       // bit-array width
#define CHUNK     128         // columns handled per workgroup
#define WPN       4           // u32 words per neuron row (CHUNK/32)
#define THREADS   256

// One workgroup evaluates the full 33-layer NAND circuit for a 128-column
// slice. State is bit-packed in LDS: [2][4096][4] u32 = 128 KiB, double-
// buffered (layer L reads buf[cur], writes buf[cur^1], one barrier/layer).
// Column<->bit mapping (consistent between pack and unpack):
//   local column 4*b + j  <->  word j, bit b   (b = lane&31, j = uint4 comp)
// Output dtype: the harness materializes bool outputs as int32 (verified:
// round-1 absmax was exactly float(1.0f).view(int32) - 1) -> write 1u/0u.
__global__ __launch_bounds__(THREADS, 1)
void nand_graph_kernel(const uint32_t* __restrict__ in,         // [1024][W], nonzero = true
                       const int*      __restrict__ idx_first,  // [NN][2]
                       const uint32_t* __restrict__ mask_first, // [NN], nonzero = invert
                       const int*      __restrict__ idx_mid,    // [NMID][NN][2]
                       const uint32_t* __restrict__ mask_mid,   // [NMID][NN]
                       const int*      __restrict__ idx_last,   // [NOUTPUTS][2]
                       const uint32_t* __restrict__ mask_last,  // [NOUTPUTS]
                       uint32_t*       __restrict__ out)        // [NOUTPUTS][W] int32 0/1
{
    __shared__ uint32_t lds[2 * NN * WPN];      // 128 KiB
    uint32_t* buf0 = lds;
    uint32_t* buf1 = lds + NN * WPN;

    const int t      = threadIdx.x;
    const int l      = t & 63;          // lane in wave
    const int wv     = t >> 6;          // wave id 0..3
    const int lane32 = l & 31;
    const int half   = l >> 5;          // 0 or 1 (low/high half of wave)
    const int shift  = half ? 32 : 0;
    const int c0     = blockIdx.x * CHUNK;

    // ---------------- pack phase: input bits -> buf1[row][word] ----------------
    // Per iteration each wave covers 16 rows (8 ballot-groups x 2 rows).
    // Lane l loads uint4 from row (rbase + 2u), cols c0 + (l&31)*4 .. +3.
    for (int it = 0; it < NINPUTS / 64; ++it) {          // 16 iterations
        const int rbase = it * 64 + wv * 16 + half;
        uint4 v[8];
        #pragma unroll
        for (int u = 0; u < 8; ++u) {
            const uint32_t* p = in + (size_t)(rbase + 2 * u) * W + c0 + lane32 * 4;
            v[u] = *(const uint4*)p;
        }
        #pragma unroll
        for (int u = 0; u < 8; ++u) {
            unsigned long long b0 = __ballot(v[u].x != 0u);
            unsigned long long b1 = __ballot(v[u].y != 0u);
            unsigned long long b2 = __ballot(v[u].z != 0u);
            unsigned long long b3 = __ballot(v[u].w != 0u);
            if (lane32 == 0) {                 // lanes 0 and 32 write their rows
                uint4 w;
                w.x = (uint32_t)(b0 >> shift);
                w.y = (uint32_t)(b1 >> shift);
                w.z = (uint32_t)(b2 >> shift);
                w.w = (uint32_t)(b3 >> shift);
                *(uint4*)&buf1[(rbase + 2 * u) * WPN] = w;
            }
        }
    }
    __syncthreads();

    // ---------------- layer 1: pack(buf1, rows<1024) -> buf0 ----------------
    #pragma unroll
    for (int k = 0; k < NN / THREADS; ++k) {             // 16 neurons/thread
        const int n = k * THREADS + t;
        const int2 ij = ((const int2*)idx_first)[n];
        const uint32_t xm = mask_first[n] ? 0xFFFFFFFFu : 0u;
        uint4 a = *(const uint4*)&buf1[ij.x * WPN];
        uint4 b = *(const uint4*)&buf1[ij.y * WPN];
        uint4 r;
        r.x = (a.x & b.x) ^ xm;  r.y = (a.y & b.y) ^ xm;
        r.z = (a.z & b.z) ^ xm;  r.w = (a.w & b.w) ^ xm;
        *(uint4*)&buf0[n * WPN] = r;
    }
    __syncthreads();

    // ---------------- 31 middle layers, ping-pong buf0 <-> buf1 ----------------
    int cur = 0;
    for (int L = 0; L < NMID; ++L) {
        const uint32_t* src = cur ? buf1 : buf0;
        uint32_t*       dst = cur ? buf0 : buf1;
        const int*      idxL = idx_mid + (size_t)L * NN * 2;
        const uint32_t* mL   = mask_mid + (size_t)L * NN;
        #pragma unroll
        for (int k = 0; k < NN / THREADS; ++k) {
            const int n = k * THREADS + t;
            const int2 ij = ((const int2*)idxL)[n];
            const uint32_t xm = mL[n] ? 0xFFFFFFFFu : 0u;
            uint4 a = *(const uint4*)&src[ij.x * WPN];
            uint4 b = *(const uint4*)&src[ij.y * WPN];
            uint4 r;
            r.x = (a.x & b.x) ^ xm;  r.y = (a.y & b.y) ^ xm;
            r.z = (a.z & b.z) ^ xm;  r.w = (a.w & b.w) ^ xm;
            *(uint4*)&dst[n * WPN] = r;
        }
        __syncthreads();
        cur ^= 1;
    }
    // final state is in buf[cur] (cur == 1 after 31 layers -> buf1)

    // ---------------- last layer: state -> result rows (stored in other buf) ----
    const uint32_t* fsrc = cur ? buf1 : buf0;
    uint32_t*       res  = cur ? buf0 : buf1;
    #pragma unroll
    for (int k = 0; k < NOUTPUTS / THREADS; ++k) {       // 4 outputs/thread
        const int o = k * THREADS + t;
        const int2 ij = ((const int2*)idx_last)[o];
        const uint32_t xm = mask_last[o] ? 0xFFFFFFFFu : 0u;
        uint4 a = *(const uint4*)&fsrc[ij.x * WPN];
        uint4 b = *(const uint4*)&fsrc[ij.y * WPN];
        uint4 r;
        r.x = (a.x & b.x) ^ xm;  r.y = (a.y & b.y) ^ xm;
        r.z = (a.z & b.z) ^ xm;  r.w = (a.w & b.w) ^ xm;
        *(uint4*)&res[o * WPN] = r;
    }
    __syncthreads();

    // ---------------- unpack: result bits -> int32 0/1 output ----------------
    // Inverse of the pack mapping: out col c0 + 4*(l&31) + j = word j bit (l&31).
    for (int it = 0; it < NOUTPUTS / 8; ++it) {          // 128 iterations
        const int r = it * 8 + wv * 2 + half;
        const uint4 w = *(const uint4*)&res[r * WPN];    // broadcast read
        uint4 v;
        v.x = (w.x >> lane32) & 1u;
        v.y = (w.y >> lane32) & 1u;
        v.z = (w.z >> lane32) & 1u;
        v.w = (w.w >> lane32) & 1u;
        *(uint4*)(out + (size_t)r * W + c0 + lane32 * 4) = v;
    }
}

extern "C" void kernel_launch(void* const* d_in, const int* in_sizes, int n_in,
                              void* d_out, int out_size, void* d_ws, size_t ws_size,
                              hipStream_t stream) {
    const uint32_t* in         = (const uint32_t*)d_in[0];  // bool as 4-byte 0/1
    const int*      idx_first  = (const int*)d_in[1];
    const uint32_t* mask_first = (const uint32_t*)d_in[2];
    const int*      idx_mid    = (const int*)d_in[3];
    const uint32_t* mask_mid   = (const uint32_t*)d_in[4];
    const int*      idx_last   = (const int*)d_in[5];
    const uint32_t* mask_last  = (const uint32_t*)d_in[6];
    uint32_t*       out        = (uint32_t*)d_out;

    nand_graph_kernel<<<W / CHUNK, THREADS, 0, stream>>>(
        in, idx_first, mask_first, idx_mid, mask_mid, idx_last, mask_last, out);
}

// Round 3
// 218.252 us; speedup vs baseline: 1.2469x; 1.2469x over previous
//
#include <hip/hip_runtime.h>
#include <stdint.h>

#define NINPUTS   1024
#define NOUTPUTS  1024
#define NMID      31          // NUM_LAYERS - 1 middle layers
#define NN        4096        // neurons per layer
#define W         65536       // bit-array width
#define CHUNK     128         // columns handled per workgroup
#define WPN       4           // u32 words per neuron row (CHUNK/32)
#define THREADS   1024        // 16 waves -> 4 waves/SIMD (latency hiding)

// One workgroup evaluates the full 33-layer NAND circuit for a 128-column
// slice. State is bit-packed in LDS: [2][4096][4] u32 = 128 KiB, double-
// buffered. Column<->bit mapping (consistent between pack and unpack):
//   local column 4*b + j  <->  word j, bit b   (b = lane&31, j = uint4 comp)
// Output dtype: harness materializes bool outputs as int32 -> write 1u/0u.
__global__ __launch_bounds__(THREADS, 4)
void nand_graph_kernel(const uint32_t* __restrict__ in,         // [1024][W], nonzero = true
                       const int*      __restrict__ idx_first,  // [NN][2]
                       const uint32_t* __restrict__ mask_first, // [NN], nonzero = invert
                       const int*      __restrict__ idx_mid,    // [NMID][NN][2]
                       const uint32_t* __restrict__ mask_mid,   // [NMID][NN]
                       const int*      __restrict__ idx_last,   // [NOUTPUTS][2]
                       const uint32_t* __restrict__ mask_last,  // [NOUTPUTS]
                       uint32_t*       __restrict__ out)        // [NOUTPUTS][W] int32 0/1
{
    __shared__ uint32_t lds[2 * NN * WPN];      // 128 KiB
    uint32_t* buf0 = lds;
    uint32_t* buf1 = lds + NN * WPN;

    const int t      = threadIdx.x;
    const int l      = t & 63;          // lane in wave
    const int wv     = t >> 6;          // wave id 0..15
    const int lane32 = l & 31;
    const int half   = l >> 5;          // 0 or 1 (low/high half of wave)
    const int shift  = half ? 32 : 0;
    const int c0     = blockIdx.x * CHUNK;

    // ---------------- pack phase: input bits -> buf1[row][word] ----------------
    // Per iteration each wave covers 16 rows (8 ballot-groups x 2 rows);
    // 16 waves cover 256 rows -> 4 iterations for 1024 rows.
    for (int it = 0; it < NINPUTS / 256; ++it) {
        const int rbase = it * 256 + wv * 16 + half;
        uint4 v[8];
        #pragma unroll
        for (int u = 0; u < 8; ++u) {
            const uint32_t* p = in + (size_t)(rbase + 2 * u) * W + c0 + lane32 * 4;
            v[u] = *(const uint4*)p;
        }
        #pragma unroll
        for (int u = 0; u < 8; ++u) {
            unsigned long long b0 = __ballot(v[u].x != 0u);
            unsigned long long b1 = __ballot(v[u].y != 0u);
            unsigned long long b2 = __ballot(v[u].z != 0u);
            unsigned long long b3 = __ballot(v[u].w != 0u);
            if (lane32 == 0) {                 // lanes 0 and 32 write their rows
                uint4 w;
                w.x = (uint32_t)(b0 >> shift);
                w.y = (uint32_t)(b1 >> shift);
                w.z = (uint32_t)(b2 >> shift);
                w.w = (uint32_t)(b3 >> shift);
                *(uint4*)&buf1[(rbase + 2 * u) * WPN] = w;
            }
        }
    }
    __syncthreads();

    // ---------------- layer 1: gather(buf1, rows<1024) -> buf0 ----------------
    #pragma unroll
    for (int k = 0; k < NN / THREADS; ++k) {             // 4 neurons/thread
        const int n = k * THREADS + t;
        const int2 ij = ((const int2*)idx_first)[n];
        const uint32_t xm = mask_first[n] ? 0xFFFFFFFFu : 0u;
        uint4 a = *(const uint4*)&buf1[ij.x * WPN];
        uint4 b = *(const uint4*)&buf1[ij.y * WPN];
        uint4 r;
        r.x = (a.x & b.x) ^ xm;  r.y = (a.y & b.y) ^ xm;
        r.z = (a.z & b.z) ^ xm;  r.w = (a.w & b.w) ^ xm;
        *(uint4*)&buf0[n * WPN] = r;
    }
    __syncthreads();

    // ---------------- 31 middle layers, ping-pong buf0 <-> buf1 ----------------
    int cur = 0;
    for (int L = 0; L < NMID; ++L) {
        const uint32_t* src = cur ? buf1 : buf0;
        uint32_t*       dst = cur ? buf0 : buf1;
        const int*      idxL = idx_mid + (size_t)L * NN * 2;
        const uint32_t* mL   = mask_mid + (size_t)L * NN;
        #pragma unroll
        for (int k = 0; k < NN / THREADS; ++k) {
            const int n = k * THREADS + t;
            const int2 ij = ((const int2*)idxL)[n];
            const uint32_t xm = mL[n] ? 0xFFFFFFFFu : 0u;
            uint4 a = *(const uint4*)&src[ij.x * WPN];
            uint4 b = *(const uint4*)&src[ij.y * WPN];
            uint4 r;
            r.x = (a.x & b.x) ^ xm;  r.y = (a.y & b.y) ^ xm;
            r.z = (a.z & b.z) ^ xm;  r.w = (a.w & b.w) ^ xm;
            *(uint4*)&dst[n * WPN] = r;
        }
        __syncthreads();
        cur ^= 1;
    }
    // final state is in buf[cur] (cur == 1 after 31 layers -> buf1)

    // ---------------- last layer: state -> result rows (stored in other buf) ----
    const uint32_t* fsrc = cur ? buf1 : buf0;
    uint32_t*       res  = cur ? buf0 : buf1;
    {
        const int o = t;                                 // 1024 outputs, 1/thread
        const int2 ij = ((const int2*)idx_last)[o];
        const uint32_t xm = mask_last[o] ? 0xFFFFFFFFu : 0u;
        uint4 a = *(const uint4*)&fsrc[ij.x * WPN];
        uint4 b = *(const uint4*)&fsrc[ij.y * WPN];
        uint4 r;
        r.x = (a.x & b.x) ^ xm;  r.y = (a.y & b.y) ^ xm;
        r.z = (a.z & b.z) ^ xm;  r.w = (a.w & b.w) ^ xm;
        *(uint4*)&res[o * WPN] = r;
    }
    __syncthreads();

    // ---------------- unpack: result bits -> int32 0/1 output ----------------
    // Inverse of the pack mapping: out col c0 + 4*(l&31) + j = word j bit (l&31).
    for (int it = 0; it < NOUTPUTS / 32; ++it) {         // 32 iterations
        const int r = it * 32 + wv * 2 + half;
        const uint4 w = *(const uint4*)&res[r * WPN];    // broadcast read
        uint4 v;
        v.x = (w.x >> lane32) & 1u;
        v.y = (w.y >> lane32) & 1u;
        v.z = (w.z >> lane32) & 1u;
        v.w = (w.w >> lane32) & 1u;
        *(uint4*)(out + (size_t)r * W + c0 + lane32 * 4) = v;
    }
}

extern "C" void kernel_launch(void* const* d_in, const int* in_sizes, int n_in,
                              void* d_out, int out_size, void* d_ws, size_t ws_size,
                              hipStream_t stream) {
    const uint32_t* in         = (const uint32_t*)d_in[0];  // bool as 4-byte 0/1
    const int*      idx_first  = (const int*)d_in[1];
    const uint32_t* mask_first = (const uint32_t*)d_in[2];
    const int*      idx_mid    = (const int*)d_in[3];
    const uint32_t* mask_mid   = (const uint32_t*)d_in[4];
    const int*      idx_last   = (const int*)d_in[5];
    const uint32_t* mask_last  = (const uint32_t*)d_in[6];
    uint32_t*       out        = (uint32_t*)d_out;

    nand_graph_kernel<<<W / CHUNK, THREADS, 0, stream>>>(
        in, idx_first, mask_first, idx_mid, mask_mid, idx_last, mask_last, out);
}